// Round 6
// baseline (594.150 us; speedup 1.0000x reference)
//
#include <hip/hip_runtime.h>

#define Bn 2
#define Cn 256
#define Hn 128
#define Wn 128
#define HWn 16384
#define NCn 80

typedef __attribute__((ext_vector_type(4))) float f32x4;
typedef __attribute__((ext_vector_type(8))) short bf16x8;

__device__ __forceinline__ float blo(unsigned u) {
    union { unsigned u; float f; } x; x.u = u << 16; return x.f;
}
__device__ __forceinline__ float bhi(unsigned u) {
    union { unsigned u; float f; } x; x.u = u & 0xffff0000u; return x.f;
}
__device__ __forceinline__ unsigned short f2bf(float f) {
    union { float f; unsigned u; } x; x.f = f;
    unsigned u = x.u + 0x7fffu + ((x.u >> 16) & 1u);   // RNE
    return (unsigned short)(u >> 16);
}

// async global->LDS, 16B per lane, wave-uniform LDS base + lane*16
#define GLOAD16(gp, lp) __builtin_amdgcn_global_load_lds( \
    (__attribute__((address_space(1))) unsigned int*)(gp), \
    (__attribute__((address_space(3))) unsigned int*)(lp), 16, 0, 0)

// ---------- zero scratch ----------
__global__ void zeroK(unsigned short* z) { z[threadIdx.x] = 0; }

// ---------- x (NCHW f32) -> NHWC bf16 ----------
__global__ __launch_bounds__(256) void xinK(const float* __restrict__ x,
                                            unsigned short* __restrict__ o) {
    __shared__ float tb[32][33];
    const int b = blockIdx.z;
    const int hw0 = blockIdx.x * 32, c0 = blockIdx.y * 32;
    const int tx = threadIdx.x & 31, ty = threadIdx.x >> 5;
    const float* ip = x + ((size_t)(b * Cn + c0)) * HWn + hw0;
#pragma unroll
    for (int r = 0; r < 4; ++r) tb[ty + 8 * r][tx] = ip[(size_t)(ty + 8 * r) * HWn + tx];
    __syncthreads();
    unsigned short* op = o + ((size_t)(b * HWn + hw0)) * Cn + c0;
#pragma unroll
    for (int r = 0; r < 4; ++r) op[(size_t)(ty + 8 * r) * Cn + tx] = f2bf(tb[tx][ty + 8 * r]);
}

// ---------- fused weight repack (coalesced): 9x (O,I,3,3) f32 -> [w][k][oc][ic] bf16 ----------
struct WPtrs { const float* p[9]; };
__global__ __launch_bounds__(256) void repackAll(WPtrs wsrc, unsigned short* __restrict__ dst) {
    const int t = blockIdx.x * 256 + threadIdx.x;     // < 589824
    const int widx = t >> 16;                          // 0..8
    const int r = t & 65535;                           // oc*256+ic
    const float* s = wsrc.p[widx] + (size_t)r * 9;
    float v[9];
#pragma unroll
    for (int k = 0; k < 9; ++k) v[k] = s[k];
    unsigned short* d = dst + (size_t)widx * 589824 + r;
#pragma unroll
    for (int k = 0; k < 9; ++k) d[(size_t)k * 65536] = f2bf(v[k]);
}

// ---------- fused head repack ----------
struct HPtrs { const float* w[3]; };
__global__ __launch_bounds__(256) void repackHeads(HPtrs hs, unsigned short* __restrict__ dst) {
    const int t = blockIdx.x * 256 + threadIdx.x;     // < 160*256
    const int ic = t & 255, row = t >> 8;
    int which, oc, OC;
    if (row < 32)       { which = 0; oc = row;       OC = 27; }
    else if (row < 128) { which = 1; oc = row - 32;  OC = 80; }
    else                { which = 2; oc = row - 128; OC = 18; }
    dst[t] = (oc < OC) ? f2bf(hs.w[which][(size_t)oc * Cn + ic]) : (unsigned short)0;
}

// ---------- 256x256 implicit-GEMM 3x3 conv (dual-job), NHWC bf16 -> NHWC bf16 ----------
// grid (128, 1, NJ), block 512 (8 waves, 2 oc x 4 px), tile 256oc x 256px, BK=64
// (fm,fn)=(8,4): 42.7 FLOP per LDS byte (vs 32 at 128^2) -> LDS-BW relief.
struct CJobs {
    const unsigned short* feat[2];
    const unsigned short* W[2];
    const float* bias[2];
    unsigned short* out[2];
};
__global__ __launch_bounds__(512, 2) void convGemm256(CJobs jobs,
                                                      const unsigned short* __restrict__ zb) {
    const int jz = blockIdx.z;
    const unsigned short* feat = jobs.feat[jz];
    const unsigned short* Wp = jobs.W[jz];
    const float* bias = jobs.bias[jz];
    unsigned short* outp = jobs.out[jz];

    __shared__ __align__(16) unsigned short lA[2][16384];   // 256oc x 64ch
    __shared__ __align__(16) unsigned short lB[2][16384];   // 256px x 64ch
    const int tid = threadIdx.x;
    const int l = tid & 63, w = tid >> 6;
    const int w_oc = w & 1, w_px = w >> 1;        // 2 x 4
    const int g = (blockIdx.x & 7) * 16 + (blockIdx.x >> 3);   // XCD-chunked, 128 tiles
    const int ry0 = g * 2;                         // first of 2 image rows
    const int b = ry0 >> 7, y0 = ry0 & 127;        // y0 even, y0+1 <= 127
    const int lr = l & 15, lg = l >> 4;

    int rI[4], cI[4], dI[4];
#pragma unroll
    for (int i = 0; i < 4; ++i) {
        int ps = (i * 8 + w) * 64 + l;            // 2048 slots = 256 rows x 8 chunks
        rI[i] = ps >> 3;
        cI[i] = ((ps & 7) ^ (rI[i] & 7)) * 8;     // pre-swizzled source chunk
        dI[i] = (i * 8 + w) * 512;                // wave-uniform LDS elem base
    }

    f32x4 acc[8][4];
#pragma unroll
    for (int i = 0; i < 8; ++i)
#pragma unroll
        for (int j = 0; j < 4; ++j) acc[i][j] = (f32x4){0.f, 0.f, 0.f, 0.f};

    auto stage = [&](int p, int bufIdx) {
        const int k = p >> 2, c0 = (p & 3) * 64;
        const int dy = k / 3 - 1, dx = k % 3 - 1;
        const unsigned short* wk = Wp + (size_t)k * 65536 + c0;
        unsigned short* la = lA[bufIdx];
        unsigned short* lb = lB[bufIdx];
#pragma unroll
        for (int i = 0; i < 4; ++i)
            GLOAD16(wk + rI[i] * Cn + cI[i], la + dI[i]);
#pragma unroll
        for (int i = 0; i < 4; ++i) {
            const int s = rI[i];
            const int yy = y0 + (s >> 7) + dy;
            const int xx = (s & 127) + dx;
            const bool v = ((unsigned)yy < (unsigned)Hn) && ((unsigned)xx < (unsigned)Wn);
            const unsigned short* gp = v
                ? feat + (((size_t)(b * Hn + yy)) * Wn + xx) * Cn + c0 + cI[i]
                : zb;
            GLOAD16(gp, lb + dI[i]);
        }
    };

    stage(0, 0);
    __syncthreads();

#pragma unroll 1
    for (int p = 0; p < 36; ++p) {
        const int cur = p & 1;
        if (p < 35) stage(p + 1, cur ^ 1);      // async, overlaps MFMA below
        const unsigned short* la = lA[cur];
        const unsigned short* lb = lB[cur];
#pragma unroll
        for (int h = 0; h < 2; ++h) {
            const int ch = h * 4 + lg;
            bf16x8 av[8], bv[4];
#pragma unroll
            for (int fm = 0; fm < 8; ++fm) {
                const int row = w_oc * 128 + fm * 16 + lr;
                av[fm] = *(const bf16x8*)&la[row * 64 + ((ch ^ (row & 7)) * 8)];
            }
#pragma unroll
            for (int fn = 0; fn < 4; ++fn) {
                const int row = w_px * 64 + fn * 16 + lr;
                bv[fn] = *(const bf16x8*)&lb[row * 64 + ((ch ^ (row & 7)) * 8)];
            }
#pragma unroll
            for (int fm = 0; fm < 8; ++fm)
#pragma unroll
                for (int fn = 0; fn < 4; ++fn)
                    acc[fm][fn] = __builtin_amdgcn_mfma_f32_16x16x32_bf16(
                        av[fm], bv[fn], acc[fm][fn], 0, 0, 0);
        }
        __syncthreads();
    }

#pragma unroll
    for (int fm = 0; fm < 8; ++fm) {
        const int oc = w_oc * 128 + fm * 16 + lg * 4;
        const float b0 = bias[oc], b1 = bias[oc + 1], b2 = bias[oc + 2], b3 = bias[oc + 3];
#pragma unroll
        for (int fn = 0; fn < 4; ++fn) {
            const int px = w_px * 64 + fn * 16 + lr;     // 0..255
            f32x4 v = acc[fm][fn];
            unsigned u0 = (unsigned)f2bf(fmaxf(v[0] + b0, 0.f)) | ((unsigned)f2bf(fmaxf(v[1] + b1, 0.f)) << 16);
            unsigned u1 = (unsigned)f2bf(fmaxf(v[2] + b2, 0.f)) | ((unsigned)f2bf(fmaxf(v[3] + b3, 0.f)) << 16);
            uint2 st; st.x = u0; st.y = u1;
            *(uint2*)&outp[(((size_t)(ry0 + (px >> 7))) * Wn + (px & 127)) * Cn + oc] = st;
        }
    }
}

// ---------- 128^2 implicit-GEMM 3x3 conv (single job, for init conv) ----------
__global__ __launch_bounds__(256, 2) void convGemm(const unsigned short* __restrict__ feat,
                                                   const unsigned short* __restrict__ Wp,
                                                   const float* __restrict__ bias,
                                                   const unsigned short* __restrict__ zb,
                                                   unsigned short* __restrict__ out) {
    __shared__ __align__(16) unsigned short lA[2][8192];
    __shared__ __align__(16) unsigned short lB[2][8192];
    const int tid = threadIdx.x;
    const int l = tid & 63, w = tid >> 6;
    const int w_oc = w & 1, w_px = w >> 1;
    const int ry = (blockIdx.x & 7) * 32 + (blockIdx.x >> 3);
    const int b = ry >> 7, y = ry & 127;
    const int oc0 = blockIdx.y * 128;
    const int lr = l & 15, lg = l >> 4;

    int rI[4], cI[4], dI[4];
#pragma unroll
    for (int i = 0; i < 4; ++i) {
        int ps = (i * 4 + w) * 64 + l;
        rI[i] = ps >> 3;
        cI[i] = ((ps & 7) ^ (rI[i] & 7)) * 8;
        dI[i] = (i * 4 + w) * 512;
    }

    f32x4 acc[4][4];
#pragma unroll
    for (int i = 0; i < 4; ++i)
#pragma unroll
        for (int j = 0; j < 4; ++j) acc[i][j] = (f32x4){0.f, 0.f, 0.f, 0.f};

    auto stage = [&](int p, int bufIdx) {
        const int k = p >> 2, c0 = (p & 3) * 64;
        const int dy = k / 3 - 1, dx = k % 3 - 1;
        const int yy = y + dy;
        const bool vy = (unsigned)yy < (unsigned)Hn;
        const size_t fbase = ((size_t)(b * Hn + yy)) * Wn;
        const unsigned short* wk = Wp + (size_t)k * 65536 + (size_t)oc0 * Cn + c0;
        unsigned short* la = lA[bufIdx];
        unsigned short* lb = lB[bufIdx];
#pragma unroll
        for (int i = 0; i < 4; ++i)
            GLOAD16(wk + rI[i] * Cn + cI[i], la + dI[i]);
#pragma unroll
        for (int i = 0; i < 4; ++i) {
            const int pxs = rI[i] + dx;
            const unsigned short* g = (vy && (unsigned)pxs < (unsigned)Wn)
                ? feat + ((fbase + pxs) * Cn + c0 + cI[i])
                : zb;
            GLOAD16(g, lb + dI[i]);
        }
    };

    stage(0, 0);
    __syncthreads();

#pragma unroll 1
    for (int p = 0; p < 36; ++p) {
        const int cur = p & 1;
        if (p < 35) stage(p + 1, cur ^ 1);
        const unsigned short* la = lA[cur];
        const unsigned short* lb = lB[cur];
#pragma unroll
        for (int h = 0; h < 2; ++h) {
            const int ch = h * 4 + lg;
            bf16x8 av[4], bv[4];
#pragma unroll
            for (int fm = 0; fm < 4; ++fm) {
                const int row = w_oc * 64 + fm * 16 + lr;
                av[fm] = *(const bf16x8*)&la[row * 64 + ((ch ^ (row & 7)) * 8)];
            }
#pragma unroll
            for (int fn = 0; fn < 4; ++fn) {
                const int row = w_px * 64 + fn * 16 + lr;
                bv[fn] = *(const bf16x8*)&lb[row * 64 + ((ch ^ (row & 7)) * 8)];
            }
#pragma unroll
            for (int fm = 0; fm < 4; ++fm)
#pragma unroll
                for (int fn = 0; fn < 4; ++fn)
                    acc[fm][fn] = __builtin_amdgcn_mfma_f32_16x16x32_bf16(
                        av[fm], bv[fn], acc[fm][fn], 0, 0, 0);
        }
        __syncthreads();
    }

#pragma unroll
    for (int fm = 0; fm < 4; ++fm) {
        const int ocb = oc0 + w_oc * 64 + fm * 16 + lg * 4;
        const float b0 = bias[ocb], b1 = bias[ocb + 1], b2 = bias[ocb + 2], b3 = bias[ocb + 3];
#pragma unroll
        for (int fn = 0; fn < 4; ++fn) {
            const int px = w_px * 64 + fn * 16 + lr;
            f32x4 v = acc[fm][fn];
            unsigned u0 = (unsigned)f2bf(fmaxf(v[0] + b0, 0.f)) | ((unsigned)f2bf(fmaxf(v[1] + b1, 0.f)) << 16);
            unsigned u1 = (unsigned)f2bf(fmaxf(v[2] + b2, 0.f)) | ((unsigned)f2bf(fmaxf(v[3] + b3, 0.f)) << 16);
            uint2 st; st.x = u0; st.y = u1;
            *(uint2*)&out[((size_t)ry * Wn + px) * Cn + ocb] = st;
        }
    }
}

// ---------- deformable conv: 256oc x 128px sampled implicit GEMM, dual-job ----------
// grid (512), block 512 (8 waves, 4 oc x 2 px), BK=64, (fm,fn)=(4,4), T14 split.
struct DJobs {
    const unsigned short* feat[2];
    const unsigned short* W[2];
    unsigned short* out[2];
    int mask[2];
};
__global__ __launch_bounds__(512, 2) void dcnGemm(DJobs jobs,
                                                  const float* __restrict__ o27) {
    const int jz = blockIdx.x >> 8;
    const unsigned short* feat = jobs.feat[jz];
    const unsigned short* Wp = jobs.W[jz];
    unsigned short* outp = jobs.out[jz];
    const bool HASMASK = jobs.mask[jz] != 0;

    __shared__ __align__(16) unsigned short lA[2][16384];   // 256oc x 64ch
    __shared__ __align__(16) unsigned short lB[2][8192];    // 128px x 64ch
    const int tid = threadIdx.x;
    const int l = tid & 63, w = tid >> 6;
    const int w_oc = w & 3, w_px = w >> 2;      // 4 x 2
    const int lb_ = blockIdx.x & 255;
    const int g = (lb_ & 7) * 32 + (lb_ >> 3);  // XCD-chunked: g = image row 0..255
    const int b = g >> 7, y = g & 127;
    const int lr = l & 15, lg = l >> 4;

    int rIA[4], cIA[4], dIA[4];
#pragma unroll
    for (int i = 0; i < 4; ++i) {
        int ps = (i * 8 + w) * 64 + l;          // 2048 slots (256 rows x 8)
        rIA[i] = ps >> 3;
        cIA[i] = ((ps & 7) ^ (rIA[i] & 7)) * 8;
        dIA[i] = (i * 8 + w) * 512;
    }

    const int sp = tid >> 2;            // sampled px 0..127
    const int pc0 = (tid & 3) * 2;      // 2 chunk-slots per thread

    const float* ob = o27 + (size_t)b * 27 * HWn + y * Wn + sp;
    const unsigned short* fb = feat + (size_t)b * HWn * Cn;

    f32x4 acc[4][4];
#pragma unroll
    for (int i = 0; i < 4; ++i)
#pragma unroll
        for (int j = 0; j < 4; ++j) acc[i][j] = (f32x4){0.f, 0.f, 0.f, 0.f};

    int ci0, ci1, ci2, ci3;
    float cw0, cw1, cw2, cw3;

    auto sampParams = [&](int k) {
        const float offy = ob[(size_t)(2 * k) * HWn];
        const float offx = ob[(size_t)(2 * k + 1) * HWn];
        const float m = HASMASK ? ob[(size_t)(18 + k) * HWn] : 1.f;
        const float py = (float)(y + k / 3 - 1) + offy;
        const float px = (float)(sp + k % 3 - 1) + offx;
        const float y0f = floorf(py), x0f = floorf(px);
        const float wy1 = py - y0f, wx1 = px - x0f;
        const int iy0 = (int)y0f, ix0 = (int)x0f;
        const int iy1 = iy0 + 1, ix1 = ix0 + 1;
        const bool vy0 = (unsigned)iy0 < (unsigned)Hn, vy1 = (unsigned)iy1 < (unsigned)Hn;
        const bool vx0 = (unsigned)ix0 < (unsigned)Wn, vx1 = (unsigned)ix1 < (unsigned)Wn;
        const int yc0 = min(max(iy0, 0), Hn - 1), yc1 = min(max(iy1, 0), Hn - 1);
        const int xc0 = min(max(ix0, 0), Wn - 1), xc1 = min(max(ix1, 0), Wn - 1);
        cw0 = (vy0 && vx0) ? (1.f - wy1) * (1.f - wx1) * m : 0.f;
        cw1 = (vy0 && vx1) ? (1.f - wy1) * wx1 * m : 0.f;
        cw2 = (vy1 && vx0) ? wy1 * (1.f - wx1) * m : 0.f;
        cw3 = (vy1 && vx1) ? wy1 * wx1 * m : 0.f;
        ci0 = (yc0 * Wn + xc0) * Cn;
        ci1 = (yc0 * Wn + xc1) * Cn;
        ci2 = (yc1 * Wn + xc0) * Cn;
        ci3 = (yc1 * Wn + xc1) * Cn;
    };

    int4 qa0, qa1, qa2, qa3;   // slot 0 corners
    int4 qb0, qb1, qb2, qb3;   // slot 1 corners
    auto cornerLoads = [&](int p) {
        const int cbA = (p & 3) * 64 + pc0 * 8;
        const int cbB = cbA + 8;
        qa0 = *(const int4*)(fb + ci0 + cbA);
        qa1 = *(const int4*)(fb + ci1 + cbA);
        qa2 = *(const int4*)(fb + ci2 + cbA);
        qa3 = *(const int4*)(fb + ci3 + cbA);
        qb0 = *(const int4*)(fb + ci0 + cbB);
        qb1 = *(const int4*)(fb + ci1 + cbB);
        qb2 = *(const int4*)(fb + ci2 + cbB);
        qb3 = *(const int4*)(fb + ci3 + cbB);
    };
    auto stageA = [&](int p, int bufIdx) {
        const int k = p >> 2, c0 = (p & 3) * 64;
        const unsigned short* wk = Wp + (size_t)k * 65536 + c0;
        unsigned short* la = lA[bufIdx];
#pragma unroll
        for (int i = 0; i < 4; ++i)
            GLOAD16(wk + rIA[i] * Cn + cIA[i], la + dIA[i]);
    };
    auto interp1 = [&](int4& c0v, int4& c1v, int4& c2v, int4& c3v) -> int4 {
        unsigned u[4];
#pragma unroll
        for (int jj = 0; jj < 4; ++jj) {
            const unsigned a0 = ((const unsigned*)&c0v)[jj];
            const unsigned a1 = ((const unsigned*)&c1v)[jj];
            const unsigned a2 = ((const unsigned*)&c2v)[jj];
            const unsigned a3 = ((const unsigned*)&c3v)[jj];
            float e0 = cw0 * blo(a0) + cw1 * blo(a1) + cw2 * blo(a2) + cw3 * blo(a3);
            float e1 = cw0 * bhi(a0) + cw1 * bhi(a1) + cw2 * bhi(a2) + cw3 * bhi(a3);
            u[jj] = (unsigned)f2bf(e0) | ((unsigned)f2bf(e1) << 16);
        }
        int4 pk; pk.x = u[0]; pk.y = u[1]; pk.z = u[2]; pk.w = u[3];
        return pk;
    };
    auto interpWrite = [&](int bufIdx) {
        int4 p0 = interp1(qa0, qa1, qa2, qa3);
        int4 p1 = interp1(qb0, qb1, qb2, qb3);
        *(int4*)&lB[bufIdx][sp * 64 + ((pc0 ^ (sp & 7)) * 8)] = p0;
        *(int4*)&lB[bufIdx][sp * 64 + (((pc0 + 1) ^ (sp & 7)) * 8)] = p1;
    };

    sampParams(0);
    stageA(0, 0);
    cornerLoads(0);
    interpWrite(0);
    __syncthreads();

#pragma unroll 1
    for (int p = 0; p < 36; ++p) {
        const int cur = p & 1;
        if (p < 35) {
            if (((p + 1) & 3) == 0) sampParams((p + 1) >> 2);
            stageA(p + 1, cur ^ 1);       // async -> lA[nxt]
            cornerLoads(p + 1);           // into regs, consumed after MFMA
        }
        const unsigned short* la = lA[cur];
        const unsigned short* lb = lB[cur];
#pragma unroll
        for (int h = 0; h < 2; ++h) {
            const int ch = h * 4 + lg;
            bf16x8 av[4], bv[4];
#pragma unroll
            for (int fm = 0; fm < 4; ++fm) {
                const int row = w_oc * 64 + fm * 16 + lr;
                av[fm] = *(const bf16x8*)&la[row * 64 + ((ch ^ (row & 7)) * 8)];
            }
#pragma unroll
            for (int fn = 0; fn < 4; ++fn) {
                const int row = w_px * 64 + fn * 16 + lr;
                bv[fn] = *(const bf16x8*)&lb[row * 64 + ((ch ^ (row & 7)) * 8)];
            }
#pragma unroll
            for (int fm = 0; fm < 4; ++fm)
#pragma unroll
                for (int fn = 0; fn < 4; ++fn)
                    acc[fm][fn] = __builtin_amdgcn_mfma_f32_16x16x32_bf16(
                        av[fm], bv[fn], acc[fm][fn], 0, 0, 0);
        }
        if (p < 35) interpWrite(cur ^ 1);   // interp + ds_write AFTER MFMA
        __syncthreads();
    }

#pragma unroll
    for (int fm = 0; fm < 4; ++fm) {
        const int oc = w_oc * 64 + fm * 16 + lg * 4;
#pragma unroll
        for (int fn = 0; fn < 4; ++fn) {
            const int px = w_px * 64 + fn * 16 + lr;
            f32x4 v = acc[fm][fn];
            unsigned u0 = (unsigned)f2bf(fmaxf(v[0], 0.f)) | ((unsigned)f2bf(fmaxf(v[1], 0.f)) << 16);
            unsigned u1 = (unsigned)f2bf(fmaxf(v[2], 0.f)) | ((unsigned)f2bf(fmaxf(v[3], 0.f)) << 16);
            uint2 stv; stv.x = u0; stv.y = u1;
            *(uint2*)&outp[((size_t)g * Wn + px) * Cn + oc] = stv;
        }
    }
}

// ---------- MFMA 1x1 head ----------
template <int OC, int PM, bool ADD, bool POST>
__global__ __launch_bounds__(256, 2) void headGemm(const unsigned short* __restrict__ feat,
                                                   const unsigned short* __restrict__ Wp,
                                                   const float* __restrict__ bias,
                                                   float* __restrict__ out,
                                                   const float* __restrict__ add,
                                                   int addC,
                                                   float* __restrict__ reg) {
    constexpr int MF = PM / 16;
    constexpr int NA = PM * 8 / 256;
    __shared__ __align__(16) unsigned short lA[PM * 64];
    __shared__ __align__(16) unsigned short lB[128 * 64];
    __shared__ float lR[POST ? 18 : 1][POST ? 128 : 1];
    const int tid = threadIdx.x;
    const int l = tid & 63, w = tid >> 6;
    const int ry = (blockIdx.x & 7) * 32 + (blockIdx.x >> 3);
    const int b = ry >> 7, y = ry & 127;
    const int lr = l & 15, lg = l >> 4;

    int rIA[NA], cIA[NA], dIA[NA];
#pragma unroll
    for (int i = 0; i < NA; ++i) {
        int ps = (i * 4 + w) * 64 + l;
        rIA[i] = ps >> 3;
        cIA[i] = ((ps & 7) ^ (rIA[i] & 7)) * 8;
        dIA[i] = (i * 4 + w) * 512;
    }
    int rIB[4], cIB[4], dIB[4];
#pragma unroll
    for (int i = 0; i < 4; ++i) {
        int ps = (i * 4 + w) * 64 + l;
        rIB[i] = ps >> 3;
        cIB[i] = ((ps & 7) ^ (rIB[i] & 7)) * 8;
        dIB[i] = (i * 4 + w) * 512;
    }

    f32x4 acc[MF][2];
#pragma unroll
    for (int i = 0; i < MF; ++i)
#pragma unroll
        for (int j = 0; j < 2; ++j) acc[i][j] = (f32x4){0.f, 0.f, 0.f, 0.f};

    const unsigned short* frow = feat + ((size_t)ry * Wn) * Cn;

#pragma unroll 1
    for (int cc = 0; cc < 4; ++cc) {
        const int c0 = cc * 64;
#pragma unroll
        for (int i = 0; i < NA; ++i)
            GLOAD16(Wp + (size_t)rIA[i] * Cn + c0 + cIA[i], &lA[dIA[i]]);
#pragma unroll
        for (int i = 0; i < 4; ++i)
            GLOAD16(frow + (size_t)rIB[i] * Cn + c0 + cIB[i], &lB[dIB[i]]);
        __syncthreads();
#pragma unroll
        for (int h = 0; h < 2; ++h) {
            const int ch = h * 4 + lg;
            bf16x8 av[MF], bv[2];
#pragma unroll
            for (int fm = 0; fm < MF; ++fm) {
                const int row = fm * 16 + lr;
                av[fm] = *(const bf16x8*)&lA[row * 64 + ((ch ^ (row & 7)) * 8)];
            }
#pragma unroll
            for (int fn = 0; fn < 2; ++fn) {
                const int row = w * 32 + fn * 16 + lr;
                bv[fn] = *(const bf16x8*)&lB[row * 64 + ((ch ^ (row & 7)) * 8)];
            }
#pragma unroll
            for (int fm = 0; fm < MF; ++fm)
#pragma unroll
                for (int fn = 0; fn < 2; ++fn)
                    acc[fm][fn] = __builtin_amdgcn_mfma_f32_16x16x32_bf16(
                        av[fm], bv[fn], acc[fm][fn], 0, 0, 0);
        }
        __syncthreads();
    }

    if (!POST) {
#pragma unroll
        for (int fm = 0; fm < MF; ++fm) {
            const int ocb = fm * 16 + lg * 4;
            if (ocb >= OC) break;
#pragma unroll
            for (int j = 0; j < 4; ++j) {
                const int oc = ocb + j;
                if (oc >= OC) break;
                const float bs = bias[oc];
#pragma unroll
                for (int fn = 0; fn < 2; ++fn) {
                    const int px = w * 32 + fn * 16 + lr;
                    float r = acc[fm][fn][j] + bs;
                    if (ADD) r += add[((size_t)(b * addC + oc)) * HWn + y * Wn + px];
                    out[((size_t)(b * OC + oc)) * HWn + y * Wn + px] = r;
                }
            }
        }
    } else {
#pragma unroll
        for (int fm = 0; fm < MF; ++fm) {
            const int ocb = fm * 16 + lg * 4;
#pragma unroll
            for (int j = 0; j < 4; ++j) {
                const int oc = ocb + j;
                if (oc < 18) {
                    const float bs = bias[oc];
#pragma unroll
                    for (int fn = 0; fn < 2; ++fn) {
                        const int px = w * 32 + fn * 16 + lr;
                        float r = acc[fm][fn][j] + bs
                                + add[((size_t)(b * addC + oc)) * HWn + y * Wn + px];
                        lR[oc][px] = r;
                    }
                }
            }
        }
        __syncthreads();
        if (tid < 128) {
            const int px = tid;
            float v[18];
#pragma unroll
            for (int c = 0; c < 18; ++c) v[c] = lR[c][px];
            float s0 = 0.f, s1 = 0.f;
#pragma unroll
            for (int q = 0; q < 9; ++q) { s0 += v[2 * q]; s1 += v[2 * q + 1]; }
            float m0 = s0 * (1.f / 9.f), m1 = s1 * (1.f / 9.f);
            float w0 = 0.f, w1 = 0.f;
#pragma unroll
            for (int q = 0; q < 9; ++q) {
                w0 = fmaxf(w0, fabsf(v[2 * q] + m0));
                w1 = fmaxf(w1, fabsf(v[2 * q + 1] + m1));
            }
            const size_t hw = (size_t)y * Wn + px;
            out[(size_t)(b * 2 + 0) * HWn + hw] = w0;
            out[(size_t)(b * 2 + 1) * HWn + hw] = w1;
            reg[(size_t)(b * 2 + 0) * HWn + hw] = m0;
            reg[(size_t)(b * 2 + 1) * HWn + hw] = m1;
        }
    }
}

// ---------- host ----------
extern "C" void kernel_launch(void* const* d_in, const int* in_sizes, int n_in,
                              void* d_out, int out_size, void* d_ws, size_t ws_size,
                              hipStream_t stream) {
    const float* x           = (const float*)d_in[0];
    const float* cls_w0      = (const float*)d_in[1];
    const float* cls_b0      = (const float*)d_in[2];
    const float* reg_w0      = (const float*)d_in[3];
    const float* reg_b0      = (const float*)d_in[4];
    const float* cls_w1      = (const float*)d_in[5];
    const float* cls_b1      = (const float*)d_in[6];
    const float* reg_w1      = (const float*)d_in[7];
    const float* reg_b1      = (const float*)d_in[8];
    const float* cls_w2      = (const float*)d_in[9];
    const float* cls_b2      = (const float*)d_in[10];
    const float* reg_w2      = (const float*)d_in[11];
    const float* reg_b2      = (const float*)d_in[12];
    const float* init_conv_w = (const float*)d_in[13];
    const float* init_conv_b = (const float*)d_in[14];
    const float* init_out_w  = (const float*)d_in[15];
    const float* init_out_b  = (const float*)d_in[16];
    const float* dcn_cls_w   = (const float*)d_in[17];
    const float* cls_out_w   = (const float*)d_in[18];
    const float* cls_out_b   = (const float*)d_in[19];
    const float* dcn_ref_w   = (const float*)d_in[20];
    const float* ref_out_w   = (const float*)d_in[21];
    const float* ref_out_b   = (const float*)d_in[22];

    float* out = (float*)d_out;

    char* ws = (char*)d_ws;
    const size_t IMG = (size_t)Bn * HWn * Cn * sizeof(unsigned short);  // 16 MiB
    unsigned short* B0 = (unsigned short*)ws; ws += IMG;
    unsigned short* B1 = (unsigned short*)ws; ws += IMG;
    unsigned short* B2 = (unsigned short*)ws; ws += IMG;
    unsigned short* B3 = (unsigned short*)ws; ws += IMG;
    float* O27 = (float*)ws; ws += (size_t)Bn * 27 * HWn * sizeof(float);
    const size_t WSZ = (size_t)9 * Cn * Cn;   // 589824 elems per weight
    unsigned short* Wpk = (unsigned short*)ws; ws += 9 * WSZ * sizeof(unsigned short);
    unsigned short* WhAll = (unsigned short*)ws; ws += 160 * Cn * sizeof(unsigned short);
    unsigned short* ZB = (unsigned short*)ws;  ws += 512;

    unsigned short* W_cls0 = Wpk + 0 * WSZ;
    unsigned short* W_cls1 = Wpk + 1 * WSZ;
    unsigned short* W_cls2 = Wpk + 2 * WSZ;
    unsigned short* W_reg0 = Wpk + 3 * WSZ;
    unsigned short* W_reg1 = Wpk + 4 * WSZ;
    unsigned short* W_reg2 = Wpk + 5 * WSZ;
    unsigned short* W_init = Wpk + 6 * WSZ;
    unsigned short* W_dcls = Wpk + 7 * WSZ;
    unsigned short* W_dref = Wpk + 8 * WSZ;
    unsigned short* Wh27 = WhAll;
    unsigned short* Wh80 = WhAll + 32 * Cn;
    unsigned short* Wh18 = WhAll + 128 * Cn;

    const dim3 blk(256);
    const dim3 blk5(512);
    const dim3 xgrd(512, 8, Bn);

    zeroK<<<1, 128, 0, stream>>>(ZB);
    WPtrs wp;
    wp.p[0] = cls_w0; wp.p[1] = cls_w1; wp.p[2] = cls_w2;
    wp.p[3] = reg_w0; wp.p[4] = reg_w1; wp.p[5] = reg_w2;
    wp.p[6] = init_conv_w; wp.p[7] = dcn_cls_w; wp.p[8] = dcn_ref_w;
    repackAll<<<2304, blk, 0, stream>>>(wp, Wpk);
    HPtrs hp; hp.w[0] = init_out_w; hp.w[1] = cls_out_w; hp.w[2] = ref_out_w;
    repackHeads<<<160, blk, 0, stream>>>(hp, WhAll);
    xinK<<<xgrd, blk, 0, stream>>>(x, B0);

    CJobs j;
    // L0 (shared input)
    j.feat[0] = B0; j.W[0] = W_cls0; j.bias[0] = cls_b0; j.out[0] = B1;
    j.feat[1] = B0; j.W[1] = W_reg0; j.bias[1] = reg_b0; j.out[1] = B2;
    convGemm256<<<dim3(128, 1, 2), blk5, 0, stream>>>(j, ZB);
    // L1
    j.feat[0] = B1; j.W[0] = W_cls1; j.bias[0] = cls_b1; j.out[0] = B3;
    j.feat[1] = B2; j.W[1] = W_reg1; j.bias[1] = reg_b1; j.out[1] = B0;
    convGemm256<<<dim3(128, 1, 2), blk5, 0, stream>>>(j, ZB);
    // L2
    j.feat[0] = B3; j.W[0] = W_cls2; j.bias[0] = cls_b2; j.out[0] = B1;   // CLS
    j.feat[1] = B0; j.W[1] = W_reg2; j.bias[1] = reg_b2; j.out[1] = B2;   // PTS
    convGemm256<<<dim3(128, 1, 2), blk5, 0, stream>>>(j, ZB);
    // init conv (single job, 128^2 kernel keeps 512 blocks in flight)
    convGemm<<<dim3(256, 2, 1), blk, 0, stream>>>(B2, W_init, init_conv_b, ZB, B3);
    headGemm<27, 32, false, false><<<256, blk, 0, stream>>>(B3, Wh27, init_out_b, O27, nullptr, 0, nullptr);
    // both DCNs in one launch
    DJobs dj;
    dj.feat[0] = B1; dj.W[0] = W_dcls; dj.out[0] = B0; dj.mask[0] = 1;
    dj.feat[1] = B2; dj.W[1] = W_dref; dj.out[1] = B3; dj.mask[1] = 0;
    dcnGemm<<<512, blk5, 0, stream>>>(dj, O27);
    // heads
    headGemm<80, 96, false, false><<<256, blk, 0, stream>>>(B0, Wh80, cls_out_b, out, nullptr, 0, nullptr);
    headGemm<18, 32, true, true><<<256, blk, 0, stream>>>(
        B3, Wh18, ref_out_b,
        out + (size_t)Bn * NCn * HWn,          // wh
        O27, 27,
        out + (size_t)Bn * NCn * HWn + (size_t)Bn * 2 * HWn);  // reg
}